// Round 13
// baseline (472.025 us; speedup 1.0000x reference)
//
#include <hip/hip_runtime.h>
#include <hip/hip_bf16.h>

// GCN forward. CSR build via two-level multisplit (radix-partition style):
//   part_hist -> part_scan -> bucket_scan -> part_scatter (single-writer
//   cachelines per block -> write-combining) -> csr_build.
// Then 3x (GEMM -> pull-aggregate -> ReLU), fused mean-pool+MLP classifier.
// norm = dinv[src]*dinv[dst] factored into GEMM / aggregate epilogues.
// G (gather table) BF16 (12.8MB): halved gather bytes (r9).
// Aggregate v4 (r13): r12 null result (pk_add no-op) proves not VALU-bound;
// req-rate math says latency-bound at ~92 outstanding/CU vs ~225 needed.
// Now 2 nodes/wave (half-wave each, 4 groups x 8 lanes), 8-deep load batches
// (deg~33 -> ~8 edges/group) = 2x loads in flight per wave.
// GEMM v3 (r10): lane=(rowhalf,colpair), 2 cols/lane -> 1 ds_read : 8 FMA.
// GEMM history: w[128]/w[64] spilled (r3/r7); KC=16 fit; now w=float2[16].
// Scatter history: naive 195MB/270us; shared-window 163MB/247us (XCD L2
// ping-pong); multisplit single-writer windows fixed it.

typedef unsigned short u16;
typedef float f32x2 __attribute__((ext_vector_type(2)));

__device__ __forceinline__ u16 f2bf(float f) {
    unsigned int x = __float_as_uint(f);
    return (u16)((x + 0x7fffu + ((x >> 16) & 1u)) >> 16);  // RNE
}

// p += {bf16lo(v), bf16hi(v)}
__device__ __forceinline__ void pk_acc(f32x2& p, unsigned int v) {
    p[0] += __uint_as_float(v << 16);
    p[1] += __uint_as_float(v & 0xffff0000u);
}
__device__ __forceinline__ void addrow_pk(const uint4 v, f32x2& p0, f32x2& p1,
                                          f32x2& p2, f32x2& p3) {
    pk_acc(p0, v.x); pk_acc(p1, v.y); pk_acc(p2, v.z); pk_acc(p3, v.w);
}

#define BMAX 2048  // buckets = ceil(N/64); N <= 131072
#define NBLK 256   // partition blocks (cntmat inner dim)

__global__ __launch_bounds__(1024) void part_hist(const int* __restrict__ dst,
                                                  int* __restrict__ cntmat,
                                                  int E, int B, int chunk) {
    __shared__ int hist[BMAX];
    for (int i = threadIdx.x; i < BMAX; i += 1024) hist[i] = 0;
    __syncthreads();
    int s = blockIdx.x * chunk;
    int en = min(s + chunk, E);
    for (int i = s + threadIdx.x; i < en; i += 1024)
        atomicAdd(&hist[dst[i] >> 6], 1);
    __syncthreads();
    for (int i = threadIdx.x; i < B; i += 1024)
        cntmat[i * NBLK + blockIdx.x] = hist[i];
}

// one wave per bucket: exclusive scan of cntmat[b][0..256) in 4x64 chunks.
__global__ __launch_bounds__(256) void part_scan(int* __restrict__ cntmat,
                                                 int* __restrict__ bcnt, int B) {
    int w = threadIdx.x >> 6;
    int lane = threadIdx.x & 63;
    int b = blockIdx.x * 4 + w;
    if (b >= B) return;
    int carry = 0;
#pragma unroll
    for (int j = 0; j < NBLK / 64; j++) {
        int idx = b * NBLK + j * 64 + lane;
        int v = cntmat[idx];
        int x = v;
#pragma unroll
        for (int d = 1; d < 64; d <<= 1) {
            int t = __shfl_up(x, d, 64);
            if (lane >= d) x += t;
        }
        cntmat[idx] = x - v + carry;          // exclusive within bucket
        carry += __shfl(x, 63, 64);           // add chunk total
    }
    if (lane == 0) bcnt[b] = carry;
}

// single block: exclusive scan of bcnt[0..M) -> prp (bucket starts).
__global__ __launch_bounds__(256) void bucket_scan(const int* __restrict__ bcnt,
                                                   int* __restrict__ prp, int M) {
    __shared__ int lds[256];
    int t = threadIdx.x;
    int base = t * 8;
    int v[8]; int ts = 0;
#pragma unroll
    for (int i = 0; i < 8; i++) { int idx = base + i; int x = (idx < M) ? bcnt[idx] : 0; v[i] = x; ts += x; }
    lds[t] = ts; __syncthreads();
#pragma unroll
    for (int d = 1; d < 256; d <<= 1) {
        int x = (t >= d) ? lds[t - d] : 0; __syncthreads();
        lds[t] += x; __syncthreads();
    }
    int run = lds[t] - ts;
#pragma unroll
    for (int i = 0; i < 8; i++) {
        int idx = base + i;
        if (idx < M) { prp[idx] = run; run += v[i]; }
    }
    if (t == 255) prp[M] = lds[255];  // == E
}

// pairs[pos] = src | (dst&63)<<17 (src < 2^17). Each block owns exclusive
// contiguous runs per bucket -> single-writer cachelines.
__global__ __launch_bounds__(1024) void part_scatter(const int* __restrict__ src,
                                                     const int* __restrict__ dst,
                                                     const int* __restrict__ cntmat,
                                                     const int* __restrict__ prp,
                                                     int* __restrict__ pairs,
                                                     int E, int B, int chunk) {
    __shared__ int cur[BMAX];
    for (int i = threadIdx.x; i < B; i += 1024)
        cur[i] = prp[i] + cntmat[i * NBLK + blockIdx.x];
    __syncthreads();
    int s = blockIdx.x * chunk;
    int en = min(s + chunk, E);
    for (int i = s + threadIdx.x; i < en; i += 1024) {
        int d = dst[i];
        int pos = atomicAdd(&cur[d >> 6], 1);
        pairs[pos] = src[i] | ((d & 63) << 17);
    }
}

// one block per bucket: local hist -> rp, dinv, csr.
__global__ __launch_bounds__(256) void csr_build(const int* __restrict__ pairs,
                                                 const int* __restrict__ prp,
                                                 int* __restrict__ rp,
                                                 float* __restrict__ dinv,
                                                 int* __restrict__ csr,
                                                 int N, int B, int E) {
    __shared__ int hist[64], cur[64];
    int b = blockIdx.x;
    int t = threadIdx.x;
    if (t < 64) hist[t] = 0;
    __syncthreads();
    int r0 = prp[b], r1 = prp[b + 1];
    for (int i = r0 + t; i < r1; i += 256)
        atomicAdd(&hist[pairs[i] >> 17], 1);
    __syncthreads();
    if (t == 0) {
        int run = r0;
        for (int k = 0; k < 64; k++) { cur[k] = run; run += hist[k]; }
    }
    __syncthreads();
    if (t < 64) {
        int node = b * 64 + t;
        if (node < N) {
            rp[node] = cur[t];
            dinv[node] = rsqrtf((float)(hist[t] + 1));  // +1 self loop
        }
    }
    if (b == B - 1 && t == 0) rp[N] = E;
    __syncthreads();
    for (int i = r0 + t; i < r1; i += 256) {
        int v = pairs[i];
        int pos = atomicAdd(&cur[v >> 17], 1);
        csr[pos] = v & 0x1FFFF;
    }
}

// G[row][j] = bf16( dinv[row] * sum_k X[row][k]*W[k][j] ), packed 2 cols/dword.
// lane = (rh, c): cols {2c,2c+1}, rows wid*16 + 2p + rh. One ds_read_b128
// (4 x-vals, wave has only 2 distinct addrs -> free broadcast) feeds 8 FMAs.
// W loaded as float2 (coalesced); 64 rows/block staged in LDS.
template <int K>
__global__ __launch_bounds__(256) void gemm_dinv(const float* __restrict__ X,
                                                 const float* __restrict__ W,
                                                 const float* __restrict__ dinv,
                                                 unsigned int* __restrict__ G2, int N) {
    constexpr int ROWS = 64;
    __shared__ float Xl[ROWS * K];
    int tid = threadIdx.x;
    int c   = tid & 31;        // column pair index: cols 2c, 2c+1
    int rh  = (tid >> 5) & 1;  // row half within pass
    int wid = tid >> 6;
    int row0 = blockIdx.x * ROWS;
    const float* xsrc = X + (size_t)row0 * K;

    if (row0 + ROWS <= N) {
#pragma unroll
        for (int i = tid; i < ROWS * K / 4; i += 256)
            ((float4*)Xl)[i] = ((const float4*)xsrc)[i];
    } else {
        int avail = (N - row0) * K;
        for (int i = tid; i < ROWS * K; i += 256)
            Xl[i] = (i < avail) ? xsrc[i] : 0.f;
    }
    __syncthreads();

    float2 acc[8];
#pragma unroll
    for (int p = 0; p < 8; p++) { acc[p].x = 0.f; acc[p].y = 0.f; }
    const float2* W2 = (const float2*)W;

#pragma unroll 1  // chunks sequential: one w[16] live at a time (no spill)
    for (int ck = 0; ck < K / 16; ck++) {
        float2 w[16];
#pragma unroll
        for (int k = 0; k < 16; k++) w[k] = W2[(ck * 16 + k) * 32 + c];
#pragma unroll
        for (int p = 0; p < 8; p++) {
            const float* xrow = &Xl[(wid * 16 + p * 2 + rh) * K + ck * 16];
#pragma unroll
            for (int k4 = 0; k4 < 4; k4++) {
                float4 xv = *(const float4*)&xrow[k4 * 4];
                acc[p].x = fmaf(xv.x, w[k4 * 4 + 0].x, acc[p].x);
                acc[p].y = fmaf(xv.x, w[k4 * 4 + 0].y, acc[p].y);
                acc[p].x = fmaf(xv.y, w[k4 * 4 + 1].x, acc[p].x);
                acc[p].y = fmaf(xv.y, w[k4 * 4 + 1].y, acc[p].y);
                acc[p].x = fmaf(xv.z, w[k4 * 4 + 2].x, acc[p].x);
                acc[p].y = fmaf(xv.z, w[k4 * 4 + 2].y, acc[p].y);
                acc[p].x = fmaf(xv.w, w[k4 * 4 + 3].x, acc[p].x);
                acc[p].y = fmaf(xv.w, w[k4 * 4 + 3].y, acc[p].y);
            }
        }
    }
#pragma unroll
    for (int p = 0; p < 8; p++) {
        int row = row0 + wid * 16 + p * 2 + rh;
        if (row < N) {
            float dn = dinv[row];
            unsigned int lo = f2bf(dn * acc[p].x);
            unsigned int hi = f2bf(dn * acc[p].y);
            G2[(size_t)row * 32 + c] = lo | (hi << 16);
        }
    }
}

// H[node] = relu(dinv[node] * (G[node] + sum_{src} G[src]) + b), G is bf16.
// v4: 2 nodes/wave (one per 32-lane half); 4 groups x 8 lanes per node;
// 8-deep load batches (deg~33 -> ~8 edges/group) = 2x loads in flight/wave.
__global__ __launch_bounds__(256) void aggregate(const unsigned int* __restrict__ G,
                                                 const int* __restrict__ rp,
                                                 const int* __restrict__ csr,
                                                 const float* __restrict__ dinv,
                                                 const float* __restrict__ bias,
                                                 float* __restrict__ H, int N) {
    int lane = threadIdx.x & 63;
    int h    = lane >> 5;                       // half-wave: node select
    int node = blockIdx.x * 8 + (threadIdx.x >> 6) * 2 + h;
    if (node >= N) return;
    int grp = (lane >> 3) & 3;                  // group within half: 0..3
    int sub = lane & 7;
    int beg = rp[node], end = rp[node + 1];
    const char* Gb = (const char*)G;
    unsigned int so = (unsigned int)sub << 4;   // 16B per uint4

    f32x2 p0 = {0.f, 0.f}, p1 = {0.f, 0.f}, p2 = {0.f, 0.f}, p3 = {0.f, 0.f};
    if (grp == 0) {  // self loop
        uint4 v = *(const uint4*)(Gb + (((unsigned int)node << 7) + so));
        addrow_pk(v, p0, p1, p2, p3);
    }

    int e = beg + grp;
    for (; e + 28 < end; e += 32) {             // 8 rows in flight
        uint4 v0 = *(const uint4*)(Gb + (((unsigned int)csr[e]      << 7) + so));
        uint4 v1 = *(const uint4*)(Gb + (((unsigned int)csr[e + 4]  << 7) + so));
        uint4 v2 = *(const uint4*)(Gb + (((unsigned int)csr[e + 8]  << 7) + so));
        uint4 v3 = *(const uint4*)(Gb + (((unsigned int)csr[e + 12] << 7) + so));
        uint4 v4 = *(const uint4*)(Gb + (((unsigned int)csr[e + 16] << 7) + so));
        uint4 v5 = *(const uint4*)(Gb + (((unsigned int)csr[e + 20] << 7) + so));
        uint4 v6 = *(const uint4*)(Gb + (((unsigned int)csr[e + 24] << 7) + so));
        uint4 v7 = *(const uint4*)(Gb + (((unsigned int)csr[e + 28] << 7) + so));
        addrow_pk(v0, p0, p1, p2, p3); addrow_pk(v1, p0, p1, p2, p3);
        addrow_pk(v2, p0, p1, p2, p3); addrow_pk(v3, p0, p1, p2, p3);
        addrow_pk(v4, p0, p1, p2, p3); addrow_pk(v5, p0, p1, p2, p3);
        addrow_pk(v6, p0, p1, p2, p3); addrow_pk(v7, p0, p1, p2, p3);
    }
    if (e + 12 < end) {                         // 4 rows
        uint4 v0 = *(const uint4*)(Gb + (((unsigned int)csr[e]      << 7) + so));
        uint4 v1 = *(const uint4*)(Gb + (((unsigned int)csr[e + 4]  << 7) + so));
        uint4 v2 = *(const uint4*)(Gb + (((unsigned int)csr[e + 8]  << 7) + so));
        uint4 v3 = *(const uint4*)(Gb + (((unsigned int)csr[e + 12] << 7) + so));
        addrow_pk(v0, p0, p1, p2, p3); addrow_pk(v1, p0, p1, p2, p3);
        addrow_pk(v2, p0, p1, p2, p3); addrow_pk(v3, p0, p1, p2, p3);
        e += 16;
    }
    if (e + 4 < end) {                          // 2 rows
        uint4 v0 = *(const uint4*)(Gb + (((unsigned int)csr[e]     << 7) + so));
        uint4 v1 = *(const uint4*)(Gb + (((unsigned int)csr[e + 4] << 7) + so));
        addrow_pk(v0, p0, p1, p2, p3); addrow_pk(v1, p0, p1, p2, p3);
        e += 8;
    }
    for (; e < end; e += 4) {
        uint4 v = *(const uint4*)(Gb + (((unsigned int)csr[e] << 7) + so));
        addrow_pk(v, p0, p1, p2, p3);
    }

#pragma unroll
    for (int m = 8; m <= 16; m <<= 1) {         // reduce 4 groups (within half)
        p0[0] += __shfl_xor(p0[0], m, 64); p0[1] += __shfl_xor(p0[1], m, 64);
        p1[0] += __shfl_xor(p1[0], m, 64); p1[1] += __shfl_xor(p1[1], m, 64);
        p2[0] += __shfl_xor(p2[0], m, 64); p2[1] += __shfl_xor(p2[1], m, 64);
        p3[0] += __shfl_xor(p3[0], m, 64); p3[1] += __shfl_xor(p3[1], m, 64);
    }
    if (grp == 0) {
        float dn = dinv[node];
        float4 ba = ((const float4*)bias)[sub * 2];
        float4 bb = ((const float4*)bias)[sub * 2 + 1];
        float4 r0, r1;
        r0.x = fmaxf(fmaf(dn, p0[0], ba.x), 0.f);
        r0.y = fmaxf(fmaf(dn, p0[1], ba.y), 0.f);
        r0.z = fmaxf(fmaf(dn, p1[0], ba.z), 0.f);
        r0.w = fmaxf(fmaf(dn, p1[1], ba.w), 0.f);
        r1.x = fmaxf(fmaf(dn, p2[0], bb.x), 0.f);
        r1.y = fmaxf(fmaf(dn, p2[1], bb.y), 0.f);
        r1.z = fmaxf(fmaf(dn, p3[0], bb.z), 0.f);
        r1.w = fmaxf(fmaf(dn, p3[1], bb.w), 0.f);
        ((float4*)H)[(size_t)node * 16 + sub * 2]     = r0;
        ((float4*)H)[(size_t)node * 16 + sub * 2 + 1] = r1;
    }
}

// fused: block = 1 graph (256 threads, 4-way row parallel). binary-search
// [start,end) in sorted batch, mean-pool H rows, z=relu(p@Wc1+bc1), out=z@Wc2+bc2.
__global__ __launch_bounds__(256) void pool_classify(const float* __restrict__ H,
                                                     const int* __restrict__ batch,
                                                     const float* __restrict__ Wc1,
                                                     const float* __restrict__ bc1,
                                                     const float* __restrict__ Wc2,
                                                     const float* __restrict__ bc2,
                                                     float* __restrict__ out,
                                                     int N) {
    int g = blockIdx.x;
    int t = threadIdx.x & 63;
    int w = threadIdx.x >> 6;
    __shared__ float psum[4][64];
    __shared__ float p[64];
    __shared__ float z[32];

    int lo = 0, hi = N;
    while (lo < hi) { int m = (lo + hi) >> 1; if (batch[m] < g) lo = m + 1; else hi = m; }
    int start = lo;
    int lo2 = start, hi2 = N;
    while (lo2 < hi2) { int m = (lo2 + hi2) >> 1; if (batch[m] < g + 1) lo2 = m + 1; else hi2 = m; }
    int end = lo2;

    float acc = 0.f;
    for (int n = start + w; n < end; n += 4) acc += H[(size_t)n * 64 + t];
    psum[w][t] = acc;
    __syncthreads();
    if (w == 0) {
        float inv = 1.0f / fmaxf((float)(end - start), 1.0f);
        p[t] = (psum[0][t] + psum[1][t] + psum[2][t] + psum[3][t]) * inv;
    }
    __syncthreads();
    if (threadIdx.x < 32) {
        float a = bc1[threadIdx.x];
        for (int f = 0; f < 64; f++) a = fmaf(p[f], Wc1[f * 32 + threadIdx.x], a);
        z[threadIdx.x] = fmaxf(a, 0.f);
    }
    __syncthreads();
    if (threadIdx.x < 10) {
        float a = bc2[threadIdx.x];
        for (int j = 0; j < 32; j++) a = fmaf(z[j], Wc2[j * 10 + threadIdx.x], a);
        out[(size_t)g * 10 + threadIdx.x] = a;
    }
}

extern "C" void kernel_launch(void* const* d_in, const int* in_sizes, int n_in,
                              void* d_out, int out_size, void* d_ws, size_t ws_size,
                              hipStream_t stream) {
    const float* x   = (const float*)d_in[0];
    const int*   ei  = (const int*)d_in[1];
    const int*   bat = (const int*)d_in[2];
    const float* W1  = (const float*)d_in[3];
    const float* b1  = (const float*)d_in[4];
    const float* W2  = (const float*)d_in[5];
    const float* b2  = (const float*)d_in[6];
    const float* W3  = (const float*)d_in[7];
    const float* b3  = (const float*)d_in[8];
    const float* Wc1 = (const float*)d_in[9];
    const float* bc1 = (const float*)d_in[10];
    const float* Wc2 = (const float*)d_in[11];
    const float* bc2 = (const float*)d_in[12];

    const int N  = in_sizes[0] / 128;
    const int E  = in_sizes[1] / 2;
    const int NG = out_size / 10;
    const int B  = (N + 63) >> 6;  // <= BMAX for N <= 131072
    const int* srcp = ei;
    const int* dstp = ei + E;

    char* ws = (char*)d_ws;
    size_t off = 0;
    auto alloc = [&](size_t bytes) -> void* {
        void* p = ws + off;
        off += (bytes + 255) / 256 * 256;
        return p;
    };
    unsigned int* G = (unsigned int*)alloc((size_t)N * 32 * 4);  // bf16x2 gather table
    float* H      = (float*)alloc((size_t)N * 64 * 4);
    int*   pairs  = (int*)H;  // alias: pairs (E ints) dead before first aggregate writes H
    int*   csr    = (int*)alloc((size_t)E * 4);
    int*   rp     = (int*)alloc((size_t)(N + 1) * 4);
    float* dinv   = (float*)alloc((size_t)N * 4);
    int*   bcnt   = (int*)alloc((size_t)BMAX * 4);
    int*   prp    = (int*)alloc((size_t)(BMAX + 1) * 4);
    int*   cntmat = (int*)alloc((size_t)BMAX * NBLK * 4);  // 2 MB
    (void)ws_size; (void)n_in;

    // --- CSR build (two-level multisplit) ---
    const int chunk = (E + NBLK - 1) / NBLK;
    part_hist<<<NBLK, 1024, 0, stream>>>(dstp, cntmat, E, B, chunk);
    part_scan<<<(B + 3) / 4, 256, 0, stream>>>(cntmat, bcnt, B);
    bucket_scan<<<1, 256, 0, stream>>>(bcnt, prp, B);
    part_scatter<<<NBLK, 1024, 0, stream>>>(srcp, dstp, cntmat, prp, pairs, E, B, chunk);
    csr_build<<<B, 256, 0, stream>>>(pairs, prp, rp, dinv, csr, N, B, E);

    // --- 3 GCN layers: GEMM (bf16x2-packed G out) + pull-aggregate ---
    gemm_dinv<128><<<(N + 63) / 64, 256, 0, stream>>>(x, W1, dinv, G, N);
    aggregate<<<(N + 7) / 8, 256, 0, stream>>>(G, rp, csr, dinv, b1, H, N);
    gemm_dinv<64><<<(N + 63) / 64, 256, 0, stream>>>(H, W2, dinv, G, N);
    aggregate<<<(N + 7) / 8, 256, 0, stream>>>(G, rp, csr, dinv, b2, H, N);
    gemm_dinv<64><<<(N + 63) / 64, 256, 0, stream>>>(H, W3, dinv, G, N);
    aggregate<<<(N + 7) / 8, 256, 0, stream>>>(G, rp, csr, dinv, b3, H, N);

    // --- fused mean-pool + classifier ---
    pool_classify<<<NG, 256, 0, stream>>>(H, bat, Wc1, bc1, Wc2, bc2, (float*)d_out, N);
}